// Round 3
// baseline (512.958 us; speedup 1.0000x reference)
//
#include <hip/hip_runtime.h>
#include <math.h>

// Problem constants (B=2, T=2048, D=512, H=8, hd=64, K=16, DEPTH=3)
#define TSEQ   2048
#define DM     512
#define NH     8
#define HD     64
#define KATT   16
#define NDEPTH 3
#define MROWS  4096   // B*T

typedef __attribute__((ext_vector_type(8))) short bf16x8;
typedef __attribute__((ext_vector_type(4))) float f32x4;

// f32 -> bf16 (round-to-nearest-even), bit-level
static __device__ __forceinline__ unsigned short f2b(float f) {
    unsigned int u = __float_as_uint(f);
    unsigned int r = (u + 0x7fffu + ((u >> 16) & 1u)) >> 16;
    return (unsigned short)r;
}

// global -> LDS direct copy, 16 B per lane. lds base must be wave-uniform;
// HW writes lane i's 16 B at lds + i*16 (guide §5: m97 pattern, 517->874 TF).
static __device__ __forceinline__ void load_lds16(const void* g, void* l) {
    __builtin_amdgcn_global_load_lds(
        (const __attribute__((address_space(1))) unsigned int*)g,
        (__attribute__((address_space(3))) unsigned int*)l, 16, 0, 0);
}

// ---------------------------------------------------------------------------
// Weight prep: W f32 [K x N] (per depth) -> Wt bf16 [N x K]. grid.z = depth.
// ---------------------------------------------------------------------------
__global__ __launch_bounds__(256) void transpose_w_kernel(
    const float* __restrict__ W, unsigned short* __restrict__ Wt, int Kd, int Nd)
{
    __shared__ float tile[32][33];
    const int n0 = blockIdx.x * 32, k0 = blockIdx.y * 32;
    const size_t off = (size_t)blockIdx.z * Kd * Nd;
    const float* Wd = W + off;
    unsigned short* Wtd = Wt + off;
    const int tx = threadIdx.x, ty = threadIdx.y;
#pragma unroll
    for (int r = 0; r < 32; r += 8)
        tile[ty + r][tx] = Wd[(size_t)(k0 + ty + r) * Nd + (n0 + tx)];
    __syncthreads();
#pragma unroll
    for (int r = 0; r < 32; r += 8)
        Wtd[(size_t)(n0 + ty + r) * Kd + (k0 + tx)] = f2b(tile[tx][ty + r]);
}

// ---------------------------------------------------------------------------
// LayerNorm: x f32 [4096 x 512] -> h bf16 [4096 x 512]. One wave per row.
// ---------------------------------------------------------------------------
__global__ __launch_bounds__(256) void ln_kernel(
    const float* __restrict__ x, const float* __restrict__ sc,
    const float* __restrict__ bi, unsigned short* __restrict__ h)
{
    const int wid  = blockIdx.x * 4 + (threadIdx.x >> 6);
    const int lane = threadIdx.x & 63;
    const float* xr = x + (size_t)wid * DM;
    const float4 v0 = *(const float4*)&xr[lane * 4];
    const float4 v1 = *(const float4*)&xr[256 + lane * 4];
    float s = v0.x + v0.y + v0.z + v0.w + v1.x + v1.y + v1.z + v1.w;
    float q = v0.x*v0.x + v0.y*v0.y + v0.z*v0.z + v0.w*v0.w
            + v1.x*v1.x + v1.y*v1.y + v1.z*v1.z + v1.w*v1.w;
#pragma unroll
    for (int off = 32; off; off >>= 1) {
        s += __shfl_xor(s, off, 64);
        q += __shfl_xor(q, off, 64);
    }
    const float mean = s * (1.0f / DM);
    const float var  = q * (1.0f / DM) - mean * mean;
    const float rs   = rsqrtf(var + 1e-5f);
    unsigned short* hr = h + (size_t)wid * DM;
    const int c0 = lane * 4, c1 = 256 + lane * 4;
    ushort4 o0, o1;
    o0.x = f2b((v0.x - mean) * rs * sc[c0+0] + bi[c0+0]);
    o0.y = f2b((v0.y - mean) * rs * sc[c0+1] + bi[c0+1]);
    o0.z = f2b((v0.z - mean) * rs * sc[c0+2] + bi[c0+2]);
    o0.w = f2b((v0.w - mean) * rs * sc[c0+3] + bi[c0+3]);
    o1.x = f2b((v1.x - mean) * rs * sc[c1+0] + bi[c1+0]);
    o1.y = f2b((v1.y - mean) * rs * sc[c1+1] + bi[c1+1]);
    o1.z = f2b((v1.z - mean) * rs * sc[c1+2] + bi[c1+2]);
    o1.w = f2b((v1.w - mean) * rs * sc[c1+3] + bi[c1+3]);
    *(ushort4*)&hr[c0] = o0;
    *(ushort4*)&hr[c1] = o1;
}

// ---------------------------------------------------------------------------
// Dilated attention, shuffle-free dots (see round-1 notes).
// ---------------------------------------------------------------------------
__global__ __launch_bounds__(256) void attn_kernel(
    const float* __restrict__ qkv, unsigned short* __restrict__ o, int dil)
{
    const int blk  = blockIdx.x;
    const int tile = blk & (TSEQ / 16 - 1);   // 128 query tiles
    const int bh   = blk >> 7;
    const int b    = bh >> 3, hh = bh & 7;
    const int t0   = tile * 16;
    const int wave = threadIdx.x >> 6, lane = threadIdx.x & 63;
    const int tq   = wave * 4 + (lane >> 4);  // query 0..15
    const int s    = lane & 15;               // key slot 0..15
    const int t    = t0 + tq;
    const size_t base = (size_t)b * TSEQ * 1536 + (size_t)hh * HD;

    __shared__ float p_lds[16][17];

    // ---- phase 1: scores + softmax ----
    int row = t - s * dil;
    const bool valid = (row >= 0);
    row = max(row, 0);
    const float* kr = qkv + base + (size_t)row * 1536 + 512;
    const float* qr = qkv + base + (size_t)t * 1536;
    float dot = 0.0f;
#pragma unroll
    for (int j = 0; j < 16; j++) {
        const float4 k4 = *(const float4*)&kr[j * 4];
        const float4 q4 = *(const float4*)&qr[j * 4];
        dot += q4.x * k4.x + q4.y * k4.y + q4.z * k4.z + q4.w * k4.w;
    }
    const float sc = valid ? dot * 0.125f : -1e30f;
    float m = sc;
#pragma unroll
    for (int off = 1; off < 16; off <<= 1) m = fmaxf(m, __shfl_xor(m, off, 64));
    const float p = expf(sc - m);
    float l = p;
#pragma unroll
    for (int off = 1; off < 16; off <<= 1) l += __shfl_xor(l, off, 64);
    p_lds[tq][s] = p / l;
    __syncthreads();

    // ---- phase 2: o = sum_s p * v ----
#pragma unroll
    for (int qi = 0; qi < 4; qi++) {
        const int qq = qi * 4 + wave;
        const int tt = t0 + qq;
        float acc = 0.0f;
#pragma unroll
        for (int ss = 0; ss < KATT; ss++) {
            int vr = tt - ss * dil;
            const float pw = p_lds[qq][ss];   // exactly 0 for masked slots
            vr = max(vr, 0);
            acc += pw * qkv[base + (size_t)vr * 1536 + 1024 + lane];
        }
        o[(size_t)(b * TSEQ + tt) * DM + (size_t)hh * HD + lane] = f2b(acc);
    }
}

// ---------------------------------------------------------------------------
// GEMM (m97 structure): C[M,N] = A_bf16[M,K] * Bt_bf16[N,K]^T  (+ epilogue)
//   EPI 0: outf = C                       (qkv projection, no bias)
//   EPI 1: outf = xin + C + bias          (proj / w2, fused residual)
//   EPI 2: outb = bf16(gelu(C + bias))    (w1, exact gelu)
// TM x TN block tile (TM,TN in {64,128}), 4 waves in 2x2, BK=32.
// Staging via global_load_lds 16B/lane into UNPADDED row-major [rows x 32]
// LDS (layout forced by wave-uniform-base + lane*16 semantics).
// ---------------------------------------------------------------------------
template<int EPI, int TM, int TN>
__global__ __launch_bounds__(256) void gemm_kernel(
    const unsigned short* __restrict__ A,   // M x K
    const unsigned short* __restrict__ Bt,  // N x K
    const float* __restrict__ bias,         // N (or null)
    const float* __restrict__ xin,          // M x N residual in (or null)
    float* __restrict__ outf,               // f32 out
    unsigned short* __restrict__ outb,      // bf16 out
    int M, int N, int K)
{
    constexpr int FM = TM / 32;       // 16-row frags per wave (wave covers TM/2)
    constexpr int FN = TN / 32;
    constexpr int AI = TM / 64;       // A staging instrs per wave (16 rows each)
    constexpr int BI = TN / 64;
    const int bn = blockIdx.x * TN;
    const int bm = blockIdx.y * TM;
    const int tid = threadIdx.x;
    const int wave = tid >> 6, lane = tid & 63;
    const int wm = (wave >> 1) * (TM / 2), wn = (wave & 1) * (TN / 2);
    const int ml = lane & 15, quad = lane >> 4;

    __shared__ unsigned short As[TM * 32];
    __shared__ unsigned short Bs[TN * 32];

    f32x4 acc[FM][FN] = {};

    const int srow = lane >> 2;            // row within 16-row chunk
    const int scol = (lane & 3) * 8;       // bf16 element offset within BK=32

    for (int k0 = 0; k0 < K; k0 += 32) {
        __syncthreads();   // previous tile fully consumed
#pragma unroll
        for (int j = 0; j < AI; j++) {
            const int chunk = wave * AI + j;
            load_lds16(&A[(size_t)(bm + chunk * 16 + srow) * K + k0 + scol],
                       &As[chunk * 16 * 32]);
        }
#pragma unroll
        for (int j = 0; j < BI; j++) {
            const int chunk = wave * BI + j;
            load_lds16(&Bt[(size_t)(bn + chunk * 16 + srow) * K + k0 + scol],
                       &Bs[chunk * 16 * 32]);
        }
        __syncthreads();   // drains vmcnt(0): staged data visible

        bf16x8 af[FM], bf[FN];
#pragma unroll
        for (int i = 0; i < FM; i++)
            af[i] = *(const bf16x8*)&As[(wm + i * 16 + ml) * 32 + quad * 8];
#pragma unroll
        for (int j = 0; j < FN; j++)
            bf[j] = *(const bf16x8*)&Bs[(wn + j * 16 + ml) * 32 + quad * 8];
#pragma unroll
        for (int i = 0; i < FM; i++)
#pragma unroll
            for (int j = 0; j < FN; j++)
                acc[i][j] = __builtin_amdgcn_mfma_f32_16x16x32_bf16(
                    af[i], bf[j], acc[i][j], 0, 0, 0);
    }

#pragma unroll
    for (int i = 0; i < FM; i++)
#pragma unroll
        for (int j = 0; j < FN; j++)
#pragma unroll
            for (int r = 0; r < 4; r++) {
                const int row = bm + wm + i * 16 + quad * 4 + r;  // C/D: row=quad*4+reg
                const int col = bn + wn + j * 16 + ml;            // C/D: col=lane&15
                const float v = acc[i][j][r];
                const size_t idx = (size_t)row * N + col;
                if (EPI == 0) {
                    outf[idx] = v;
                } else if (EPI == 1) {
                    outf[idx] = xin[idx] + v + bias[col];
                } else {
                    const float u = v + bias[col];
                    const float g = 0.5f * u * (1.0f + erff(u * 0.70710678118654752f));
                    outb[idx] = f2b(g);
                }
            }
}

// ---------------------------------------------------------------------------
extern "C" void kernel_launch(void* const* d_in, const int* in_sizes, int n_in,
                              void* d_out, int out_size, void* d_ws, size_t ws_size,
                              hipStream_t stream)
{
    (void)in_sizes; (void)n_in; (void)out_size; (void)ws_size;
    const float* x_in   = (const float*)d_in[0];
    const float* ln1_s  = (const float*)d_in[1];
    const float* ln1_b  = (const float*)d_in[2];
    const float* qkv_w  = (const float*)d_in[3];
    const float* proj_w = (const float*)d_in[4];
    const float* proj_b = (const float*)d_in[5];
    const float* ln2_s  = (const float*)d_in[6];
    const float* ln2_b  = (const float*)d_in[7];
    const float* w1     = (const float*)d_in[8];
    const float* b1     = (const float*)d_in[9];
    const float* w2     = (const float*)d_in[10];
    const float* b2     = (const float*)d_in[11];

    // Workspace carve-up (all 256B aligned by construction)
    char* ws = (char*)d_ws;
    float*          xbuf = (float*)(ws);                        // 8 MB f32 x
    char*           Q    = ws + 8388608;                        // shared region
    float*          qkvb = (float*)Q;                           // qkv f32 [4096x1536]
    unsigned short* ubuf = (unsigned short*)Q;                  // u bf16 [4096x2048] (reuses qkv)
    unsigned short* hbuf = (unsigned short*)(ws + 33554432);    // h bf16 [4096x512]
    unsigned short* obuf = (unsigned short*)(ws + 37748736);    // o bf16 [4096x512]
    unsigned short* qkvT = (unsigned short*)(ws + 41943040);    // [3][1536x512]
    unsigned short* projT= (unsigned short*)(ws + 46661632);    // [3][512x512]
    unsigned short* w1T  = (unsigned short*)(ws + 48234496);    // [3][2048x512]
    unsigned short* w2T  = (unsigned short*)(ws + 54525952);    // [3][512x2048]

    // x working copy
    hipMemcpyAsync(xbuf, x_in, (size_t)MROWS * DM * sizeof(float),
                   hipMemcpyDeviceToDevice, stream);

    // Pre-transpose + bf16-convert all weights: Wt[n][k]
    transpose_w_kernel<<<dim3(1536/32, 512/32, 3),  dim3(32, 8), 0, stream>>>(qkv_w,  qkvT, 512, 1536);
    transpose_w_kernel<<<dim3( 512/32, 512/32, 3),  dim3(32, 8), 0, stream>>>(proj_w, projT, 512, 512);
    transpose_w_kernel<<<dim3(2048/32, 512/32, 3),  dim3(32, 8), 0, stream>>>(w1,     w1T,  512, 2048);
    transpose_w_kernel<<<dim3( 512/32, 2048/32, 3), dim3(32, 8), 0, stream>>>(w2,     w2T, 2048, 512);

    for (int d = 0; d < NDEPTH; d++) {
        const int dil = 1 << d;
        // LN1: x -> h (bf16)
        ln_kernel<<<MROWS / 4, 256, 0, stream>>>(xbuf, ln1_s + d * DM, ln1_b + d * DM, hbuf);
        // qkv = h @ qkv_w  (f32 out, no bias). 24x32=768 blocks (3/CU).
        gemm_kernel<0, 128, 64><<<dim3(1536/64, MROWS/128), 256, 0, stream>>>(
            hbuf, qkvT + (size_t)d * 1536 * 512, nullptr, nullptr, qkvb, nullptr,
            MROWS, 1536, 512);
        // dilated attention -> o (bf16)
        attn_kernel<<<2 * NH * (TSEQ / 16), 256, 0, stream>>>(qkvb, obuf, dil);
        // x = x + o @ proj_w + proj_b. 8x32=256 blocks.
        gemm_kernel<1, 128, 64><<<dim3(512/64, MROWS/128), 256, 0, stream>>>(
            obuf, projT + (size_t)d * 512 * 512, proj_b + d * DM, xbuf, xbuf, nullptr,
            MROWS, 512, 512);
        // LN2: x -> h (bf16)
        ln_kernel<<<MROWS / 4, 256, 0, stream>>>(xbuf, ln2_s + d * DM, ln2_b + d * DM, hbuf);
        // u = gelu(h @ w1 + b1) (bf16 out). 16x32=512 blocks (2/CU).
        gemm_kernel<2, 128, 128><<<dim3(2048/128, MROWS/128), 256, 0, stream>>>(
            hbuf, w1T + (size_t)d * 2048 * 512, b1 + d * 2048, nullptr, nullptr, ubuf,
            MROWS, 2048, 512);
        // x = x + u @ w2 + b2 ; final depth writes straight to d_out. 256 blocks.
        float* xout = (d == NDEPTH - 1) ? (float*)d_out : xbuf;
        gemm_kernel<1, 128, 64><<<dim3(512/64, MROWS/128), 256, 0, stream>>>(
            ubuf, w2T + (size_t)d * 512 * 2048, b2 + d * DM, xbuf, xout, nullptr,
            MROWS, 512, 2048);
    }
}